// Round 2
// baseline (1482.095 us; speedup 1.0000x reference)
//
#include <hip/hip_runtime.h>
#include <hip/hip_bf16.h>

#define NN 8192      // nodes
#define NE 24576     // edges
#define HID 100

// ---------------------------------------------------------------------------
// init: idx_i/idx_o = -1 (so unwritten entries are skipped, never poison),
// mi/mo = 0.  Replaces hipMemsetAsync (suspect in graph-capture abort).
// ---------------------------------------------------------------------------
__global__ __launch_bounds__(256) void init_kernel(int* __restrict__ idx,
                                                   float* __restrict__ acc)
{
    int t = blockIdx.x * blockDim.x + threadIdx.x;
    if (t < 2 * NE) idx[t] = -1;
    if (t < 2 * NN * 4) acc[t] = 0.0f;
}

// ---------------------------------------------------------------------------
// scan (bf16 elements): matrices are [NN, NE] row-major, one nonzero per
// column.  Stream as uint4 (8 bf16), skip all-zero chunks (density 1.2e-4).
// ---------------------------------------------------------------------------
__global__ __launch_bounds__(256) void scan16_kernel(
    const unsigned short* __restrict__ Ri,
    const unsigned short* __restrict__ Ro,
    int* __restrict__ idx_i,
    int* __restrict__ idx_o)
{
    const unsigned chunksPerMat = (unsigned)NN * NE / 8u;
    const unsigned total = chunksPerMat * 2u;
    const unsigned stride = gridDim.x * blockDim.x;
    for (unsigned c = blockIdx.x * blockDim.x + threadIdx.x; c < total; c += stride) {
        const unsigned short* src;
        int* dst;
        unsigned cc;
        if (c < chunksPerMat) { src = Ri; dst = idx_i; cc = c; }
        else                  { src = Ro; dst = idx_o; cc = c - chunksPerMat; }
        uint4 v = ((const uint4*)src)[cc];
        if ((v.x | v.y | v.z | v.w) == 0u) continue;
        unsigned base = cc * 8u;
        unsigned n = base / NE;
        unsigned k = base - n * NE;
        unsigned w[4] = {v.x, v.y, v.z, v.w};
        #pragma unroll
        for (int i = 0; i < 4; ++i) {
            if (w[i] & 0xFFFFu) dst[k + 2*i]     = (int)n;
            if (w[i] >> 16)     dst[k + 2*i + 1] = (int)n;
        }
    }
}

// scan (fp32 elements): uint4 = 4 fp32 per chunk.
__global__ __launch_bounds__(256) void scan32_kernel(
    const unsigned int* __restrict__ Ri,
    const unsigned int* __restrict__ Ro,
    int* __restrict__ idx_i,
    int* __restrict__ idx_o)
{
    const unsigned chunksPerMat = (unsigned)NN * NE / 4u;
    const unsigned total = chunksPerMat * 2u;
    const unsigned stride = gridDim.x * blockDim.x;
    for (unsigned c = blockIdx.x * blockDim.x + threadIdx.x; c < total; c += stride) {
        const unsigned int* src;
        int* dst;
        unsigned cc;
        if (c < chunksPerMat) { src = Ri; dst = idx_i; cc = c; }
        else                  { src = Ro; dst = idx_o; cc = c - chunksPerMat; }
        uint4 v = ((const uint4*)src)[cc];
        if ((v.x | v.y | v.z | v.w) == 0u) continue;
        unsigned base = cc * 4u;
        unsigned n = base / NE;
        unsigned k = base - n * NE;
        unsigned w[4] = {v.x, v.y, v.z, v.w};
        #pragma unroll
        for (int i = 0; i < 4; ++i)
            if (w[i] != 0u) dst[k + i] = (int)n;
    }
}

// ---------------------------------------------------------------------------
// dtype-generic load helpers
// ---------------------------------------------------------------------------
__device__ inline float ldf(const float* p)           { return *p; }
__device__ inline float ldf(const __hip_bfloat16* p)  { return __bfloat162float(*p); }

// ---------------------------------------------------------------------------
// per-edge weighted scatter with index guards:
//   mi[idx_i[k]] += e[k] * X[idx_o[k]];  mo[idx_o[k]] += e[k] * X[idx_i[k]]
// ---------------------------------------------------------------------------
template <typename T>
__global__ __launch_bounds__(256) void edge_kernel(
    const T* __restrict__ X,
    const T* __restrict__ e,
    const int* __restrict__ idx_i,
    const int* __restrict__ idx_o,
    float* __restrict__ mi,
    float* __restrict__ mo)
{
    int k = blockIdx.x * blockDim.x + threadIdx.x;
    if (k >= NE) return;
    int ni = idx_i[k];
    int no = idx_o[k];
    if ((unsigned)ni >= NN || (unsigned)no >= NN) return;  // guard: never fault
    float ew = ldf(e + k);
    #pragma unroll
    for (int d = 0; d < 4; ++d) {
        float xo = ldf(X + no * 4 + d);
        float xi = ldf(X + ni * 4 + d);
        atomicAdd(&mi[ni * 4 + d], ew * xo);
        atomicAdd(&mo[no * 4 + d], ew * xi);
    }
}

// ---------------------------------------------------------------------------
// per-node MLP: M=[mi,mo,X] (12) -> tanh dense 100 -> sigmoid dense 1.
// Weights staged in LDS fp32; broadcast reads.
// ---------------------------------------------------------------------------
template <typename T, typename TO>
__global__ __launch_bounds__(256) void mlp_kernel(
    const T* __restrict__ X,
    const float* __restrict__ mi,
    const float* __restrict__ mo,
    const T* __restrict__ W1,
    const T* __restrict__ b1,
    const T* __restrict__ W2,
    const T* __restrict__ b2,
    TO* __restrict__ out)
{
    __shared__ float sW1[12 * HID];
    __shared__ float sb1[HID];
    __shared__ float sW2[HID];
    __shared__ float sb2;
    for (int i = threadIdx.x; i < 12 * HID; i += 256)
        sW1[i] = ldf(W1 + i);
    if (threadIdx.x < HID) {
        sb1[threadIdx.x] = ldf(b1 + threadIdx.x);
        sW2[threadIdx.x] = ldf(W2 + threadIdx.x);
    }
    if (threadIdx.x == 0) sb2 = ldf(b2);
    __syncthreads();

    int n = blockIdx.x * blockDim.x + threadIdx.x;
    if (n >= NN) return;

    float M[12];
    #pragma unroll
    for (int d = 0; d < 4; ++d) {
        M[d]     = mi[n * 4 + d];
        M[4 + d] = mo[n * 4 + d];
        M[8 + d] = ldf(X + n * 4 + d);
    }
    float o = sb2;
    for (int j = 0; j < HID; ++j) {
        float acc = sb1[j];
        #pragma unroll
        for (int i = 0; i < 12; ++i)
            acc += M[i] * sW1[i * HID + j];
        o += tanhf(acc) * sW2[j];
    }
    float sig = 1.0f / (1.0f + expf(-o));
    if constexpr (sizeof(TO) == 2) out[n] = __float2bfloat16(sig);
    else                           out[n] = sig;
}

// host-side: bytes per element of an allocation (capture-safe query)
static int elem_bytes(const void* p, size_t n_elems, int dflt) {
    void* base = nullptr;
    size_t sz = 0;
    if (hipMemGetAddressRange((hipDeviceptr_t*)&base, &sz, (hipDeviceptr_t)p) != hipSuccess
        || sz == 0 || n_elems == 0)
        return dflt;
    double bpe = (double)sz / (double)n_elems;
    return (bpe >= 3.0) ? 4 : 2;
}

extern "C" void kernel_launch(void* const* d_in, const int* in_sizes, int n_in,
                              void* d_out, int out_size, void* d_ws, size_t ws_size,
                              hipStream_t stream)
{
    // workspace: idx_i[NE] | idx_o[NE] ints, then mi[NN*4] | mo[NN*4] fp32
    int*   idx_i = (int*)d_ws;
    int*   idx_o = idx_i + NE;
    float* mi    = (float*)(idx_o + NE);
    float* mo    = mi + NN * 4;

    const int in_b  = elem_bytes(d_in[2], (size_t)NN * NE, 2);
    const int out_b = elem_bytes(d_out, (size_t)(out_size > 0 ? out_size : NN), in_b);

    init_kernel<<<(2 * NN * 4) / 256, 256, 0, stream>>>(idx_i, mi);

    if (in_b == 2) {
        scan16_kernel<<<16384, 256, 0, stream>>>(
            (const unsigned short*)d_in[2], (const unsigned short*)d_in[3], idx_i, idx_o);
    } else {
        scan32_kernel<<<16384, 256, 0, stream>>>(
            (const unsigned int*)d_in[2], (const unsigned int*)d_in[3], idx_i, idx_o);
    }

    if (in_b == 2) {
        const __hip_bfloat16* X  = (const __hip_bfloat16*)d_in[0];
        const __hip_bfloat16* e  = (const __hip_bfloat16*)d_in[1];
        const __hip_bfloat16* W1 = (const __hip_bfloat16*)d_in[4];
        const __hip_bfloat16* b1 = (const __hip_bfloat16*)d_in[5];
        const __hip_bfloat16* W2 = (const __hip_bfloat16*)d_in[6];
        const __hip_bfloat16* b2 = (const __hip_bfloat16*)d_in[7];
        edge_kernel<__hip_bfloat16><<<(NE + 255) / 256, 256, 0, stream>>>(
            X, e, idx_i, idx_o, mi, mo);
        if (out_b == 2)
            mlp_kernel<__hip_bfloat16, __hip_bfloat16><<<NN / 256, 256, 0, stream>>>(
                X, mi, mo, W1, b1, W2, b2, (__hip_bfloat16*)d_out);
        else
            mlp_kernel<__hip_bfloat16, float><<<NN / 256, 256, 0, stream>>>(
                X, mi, mo, W1, b1, W2, b2, (float*)d_out);
    } else {
        const float* X  = (const float*)d_in[0];
        const float* e  = (const float*)d_in[1];
        const float* W1 = (const float*)d_in[4];
        const float* b1 = (const float*)d_in[5];
        const float* W2 = (const float*)d_in[6];
        const float* b2 = (const float*)d_in[7];
        edge_kernel<float><<<(NE + 255) / 256, 256, 0, stream>>>(
            X, e, idx_i, idx_o, mi, mo);
        if (out_b == 2)
            mlp_kernel<float, __hip_bfloat16><<<NN / 256, 256, 0, stream>>>(
                X, mi, mo, W1, b1, W2, b2, (__hip_bfloat16*)d_out);
        else
            mlp_kernel<float, float><<<NN / 256, 256, 0, stream>>>(
                X, mi, mo, W1, b1, W2, b2, (float*)d_out);
    }
}